// Round 4
// baseline (442.869 us; speedup 1.0000x reference)
//
#include <hip/hip_runtime.h>

typedef __attribute__((ext_vector_type(8))) short short8;
typedef __attribute__((ext_vector_type(4))) float f32x4;
typedef __attribute__((ext_vector_type(4))) unsigned short u16x4;

constexpr int cB = 2, cN = 4096, cE = 256, cH = 8, cHS = 32;

__device__ __forceinline__ unsigned short f2bf(float f) {
    unsigned int u = __builtin_bit_cast(unsigned int, f);
    u = (u + 0x7FFFu + ((u >> 16) & 1u)) >> 16;
    return (unsigned short)u;
}

__device__ __forceinline__ unsigned int cvt_pk_bf16(float lo, float hi) {
    unsigned int r;
    asm("v_cvt_pk_bf16_f32 %0, %1, %2" : "=v"(r) : "v"(lo), "v"(hi));
    return r;
}

// ---- f32 -> bf16 convert: node features (2M elems, 4/thread) ----
__global__ __launch_bounds__(256) void cvt_x_kernel(const float* __restrict__ x,
                                                    unsigned short* __restrict__ xb) {
    int t = blockIdx.x * 256 + threadIdx.x;   // 524288 threads exactly
    f32x4 v = *((const f32x4*)x + t);
    u16x4 o = { f2bf(v[0]), f2bf(v[1]), f2bf(v[2]), f2bf(v[3]) };
    *((u16x4*)xb + t) = o;
}

// ---- f32 -> bf16 convert: Wq|Wk|Wv -> Wcb[768][256] ----
__global__ __launch_bounds__(256) void cvt_w_kernel(const float* __restrict__ Wq,
                                                    const float* __restrict__ Wk,
                                                    const float* __restrict__ Wv,
                                                    unsigned short* __restrict__ wcb) {
    int t = blockIdx.x * 256 + threadIdx.x;   // 49152 threads exactly
    int f = t * 4;
    int o = f >> 8, i = f & 255;
    const float* src = (o < 256) ? Wq : (o < 512 ? Wk : Wv);
    f32x4 v = *(const f32x4*)(src + (size_t)(o & 255) * 256 + i);
    u16x4 ov = { f2bf(v[0]), f2bf(v[1]), f2bf(v[2]), f2bf(v[3]) };
    *((u16x4*)wcb + t) = ov;
}

// ---- adjacency (4-byte elems, nonzero == edge) -> bitmask, 64 bits/wave ----
__global__ __launch_bounds__(256) void bitpack_kernel(const int* __restrict__ adj,
                                                      unsigned long long* __restrict__ mask) {
    int lane = threadIdx.x & 63;
    int wave = blockIdx.x * 4 + (threadIdx.x >> 6);
    const int nwaves = 2048 * 4;
    const int nwords = cB * cN * cN / 64;     // 524288
    for (int w = wave; w < nwords; w += nwaves) {
        int v = adj[(size_t)w * 64 + lane];
        unsigned long long bal = __ballot(v != 0);
        if (lane == 0) mask[w] = bal;
    }
}

// ---- QKV projection: C[8192][768] = Xb @ Wcb^T + bias, MFMA 16x16x32 bf16 ----
// Q stored [b][h][n][32] bf16, PRE-SCALED by log2(e)/sqrt(HS) so attention can
// use exp2 on the raw QK^T output. K stored [b][h][n][32].
// V stored transposed AND k'-permuted within each 32-block of n:
//   Vt[h][hs][ (n&~31) + 2*(n&15) + ((n>>4)&1) ] = V[n][hs]
// so attn's packed (p_c, p_{16+c}) LDS pairs line up with contiguous V loads.
__global__ __launch_bounds__(256) void qkv_proj_kernel(const unsigned short* __restrict__ xb,
                                                       const unsigned short* __restrict__ wcb,
                                                       const float* __restrict__ bq,
                                                       const float* __restrict__ bk,
                                                       const float* __restrict__ bv,
                                                       unsigned short* __restrict__ Qb,
                                                       unsigned short* __restrict__ Kb,
                                                       unsigned short* __restrict__ Vt) {
    const int wv = threadIdx.x >> 6, lane = threadIdx.x & 63;
    const int col = lane & 15, grp = lane >> 4;
    const int rowbase = blockIdx.x * 64 + wv * 16;   // 16 rows per wave
    const int colbase = blockIdx.y * 64;             // 64 cols per block
    const float CE = 1.4426950408889634f * 0.17677669529663687f;  // log2(e)/sqrt(32)
    f32x4 acc[4] = {};
    for (int kk = 0; kk < 8; ++kk) {
        short8 a = *(const short8*)(xb + (size_t)(rowbase + col) * 256 + kk * 32 + grp * 8);
        #pragma unroll
        for (int c = 0; c < 4; ++c) {
            short8 bf = *(const short8*)(wcb + (size_t)(colbase + c * 16 + col) * 256 + kk * 32 + grp * 8);
            acc[c] = __builtin_amdgcn_mfma_f32_16x16x32_bf16(a, bf, acc[c], 0, 0, 0);
        }
    }
    #pragma unroll
    for (int c = 0; c < 4; ++c) {
        const int o = colbase + c * 16 + col;        // lane's output column
        const int sel = o >> 8, oo = o & 255;
        const float bias = (sel == 0 ? bq : sel == 1 ? bk : bv)[oo];
        const int h = oo >> 5, hs = oo & 31;
        const int R0 = rowbase + grp * 4;            // 4 consecutive rows per lane
        const int b = R0 >> 12, n0 = R0 & 4095;
        if (sel == 0) {
            #pragma unroll
            for (int r = 0; r < 4; ++r)
                Qb[(size_t)((b * cH + h) * cN + n0 + r) * cHS + hs] = f2bf((acc[c][r] + bias) * CE);
        } else if (sel == 1) {
            #pragma unroll
            for (int r = 0; r < 4; ++r)
                Kb[(size_t)((b * cH + h) * cN + n0 + r) * cHS + hs] = f2bf(acc[c][r] + bias);
        } else {
            unsigned short* vrow = Vt + (size_t)((b * cH + h) * cHS + hs) * cN;
            #pragma unroll
            for (int r = 0; r < 4; ++r) {
                const int n = n0 + r;
                const int pos = (n & ~31) + 2 * (n & 15) + ((n >> 4) & 1);
                vrow[pos] = f2bf(acc[c][r] + bias);
            }
        }
    }
}

// ---- Flash attention, fixed-max softmax (m=0), bit-masking. ----
// One BLOCK per (b, h, 32-query tile); 4 waves split the key range.
// LDS = 16 KB total and VGPR <= 64 so all 8 blocks/CU are co-resident
// (8 waves/SIMD = 100% occupancy, zero tail round).
__global__ __launch_bounds__(256, 8) void attn_kernel(const unsigned short* __restrict__ Qb,
                                                      const unsigned short* __restrict__ Kb,
                                                      const unsigned short* __restrict__ Vt,
                                                      const unsigned int* __restrict__ mask32,
                                                      float* __restrict__ out) {
    // 16 KB buffer. During the loop: per-wave P staging (2560 B at wv*2560).
    // After the loop: [wave][slot][lane] f32 combine buffer, two phases.
    __shared__ float comb[4][16][64];
    const int wv = threadIdx.x >> 6, lane = threadIdx.x & 63;
    const int col = lane & 15, grp = lane >> 4;
    int bid = blockIdx.x;
    bid = (bid & 7) * 256 + (bid >> 3);              // XCD chunk swizzle (2048 = 8*256)
    const int qt = bid & 127, h = (bid >> 7) & 7, b = bid >> 10;
    const int qbase = qt * 32;
    const unsigned short* Qh = Qb + (size_t)(b * cH + h) * cN * cHS;
    const unsigned short* Kh = Kb + (size_t)(b * cH + h) * cN * cHS;
    const unsigned short* Vh = Vt + (size_t)(b * cH + h) * cHS * cN;
    const unsigned int* mrow = mask32 + (size_t)(b * cN + qbase) * 128;
    // per-wave P staging area: [qs][16 rows][20 u32], row stride 80B
    unsigned int* pw = (unsigned int*)&comb[0][0][0] + wv * 640;

    const short8 aq0 = *(const short8*)(Qh + (size_t)(qbase + col) * cHS + grp * 8);
    const short8 aq1 = *(const short8*)(Qh + (size_t)(qbase + 16 + col) * cHS + grp * 8);

    f32x4 acc[2][2] = {};
    f32x4 lacc[2] = {};                              // row-sums via ones-MFMA
    const f32x4 z4 = {0.f, 0.f, 0.f, 0.f};
    const short8 ones = { 0x3F80, 0x3F80, 0x3F80, 0x3F80, 0x3F80, 0x3F80, 0x3F80, 0x3F80 };

    const int ktEnd = wv * 32 + 32;
    #pragma unroll 1
    for (int kt = wv * 32; kt < ktEnd; ++kt) {
        const int kbase = kt * 32;
        const short8 k0 = *(const short8*)(Kh + (size_t)(kbase + col) * cHS + grp * 8);
        const short8 k1 = *(const short8*)(Kh + (size_t)(kbase + 16 + col) * cHS + grp * 8);
        const short8 v0 = *(const short8*)(Vh + (size_t)col * cN + kbase + grp * 8);
        const short8 v1 = *(const short8*)(Vh + (size_t)(16 + col) * cN + kbase + grp * 8);

        f32x4 s[2][2];
        s[0][0] = __builtin_amdgcn_mfma_f32_16x16x32_bf16(aq0, k0, z4, 0, 0, 0);
        s[0][1] = __builtin_amdgcn_mfma_f32_16x16x32_bf16(aq0, k1, z4, 0, 0, 0);
        s[1][0] = __builtin_amdgcn_mfma_f32_16x16x32_bf16(aq1, k0, z4, 0, 0, 0);
        s[1][1] = __builtin_amdgcn_mfma_f32_16x16x32_bf16(aq1, k1, z4, 0, 0, 0);

        #pragma unroll
        for (int qs = 0; qs < 2; ++qs) {
            #pragma unroll
            for (int r = 0; r < 4; ++r) {
                const unsigned int w32 = mrow[(size_t)(qs * 16 + grp * 4 + r) * 128 + kt];
                const float e0 = __builtin_exp2f(s[qs][0][r]);
                const float e1 = __builtin_exp2f(s[qs][1][r]);
                const unsigned int msk = ((w32 >> col) & 0x00010001u) * 0xFFFFu;
                pw[qs * 320 + (grp * 4 + r) * 20 + col] = cvt_pk_bf16(e0, e1) & msk;
            }
        }
        #pragma unroll
        for (int qs = 0; qs < 2; ++qs) {
            const short8 pa = *(const short8*)(pw + qs * 320 + col * 20 + grp * 4);
            acc[qs][0] = __builtin_amdgcn_mfma_f32_16x16x32_bf16(pa, v0, acc[qs][0], 0, 0, 0);
            acc[qs][1] = __builtin_amdgcn_mfma_f32_16x16x32_bf16(pa, v1, acc[qs][1], 0, 0, 0);
            lacc[qs]   = __builtin_amdgcn_mfma_f32_16x16x32_bf16(pa, ones, lacc[qs], 0, 0, 0);
        }
    }

    // ---- two-phase combine through the same 16 KB ----
    __syncthreads();                                 // all waves done with P areas
    #pragma unroll
    for (int qs = 0; qs < 2; ++qs)
        #pragma unroll
        for (int hf = 0; hf < 2; ++hf)
            #pragma unroll
            for (int j = 0; j < 4; ++j)
                comb[wv][(qs * 2 + hf) * 4 + j][lane] = acc[qs][hf][j];
    __syncthreads();
    const int sg = wv, qs2 = sg >> 1, half = sg & 1;
    f32x4 a = {0.f, 0.f, 0.f, 0.f};
    #pragma unroll
    for (int w = 0; w < 4; ++w)
        #pragma unroll
        for (int j = 0; j < 4; ++j)
            a[j] += comb[w][sg * 4 + j][lane];
    __syncthreads();
    #pragma unroll
    for (int qs = 0; qs < 2; ++qs)
        #pragma unroll
        for (int j = 0; j < 4; ++j)
            comb[wv][qs * 4 + j][lane] = lacc[qs][j];
    __syncthreads();
    f32x4 l = {0.f, 0.f, 0.f, 0.f};
    #pragma unroll
    for (int w = 0; w < 4; ++w)
        #pragma unroll
        for (int j = 0; j < 4; ++j)
            l[j] += comb[w][qs2 * 4 + j][lane];

    const int grp2 = lane >> 4, col2 = lane & 15;
    const int row0 = qbase + qs2 * 16 + grp2 * 4;
    #pragma unroll
    for (int j = 0; j < 4; ++j) {
        out[(size_t)(b * cN + row0 + j) * cE + h * 32 + half * 16 + col2] = a[j] / l[j];
    }
}

extern "C" void kernel_launch(void* const* d_in, const int* in_sizes, int n_in,
                              void* d_out, int out_size, void* d_ws, size_t ws_size,
                              hipStream_t stream) {
    const float* x   = (const float*)d_in[0];
    const int*   adj = (const int*)d_in[1];
    const float* Wq  = (const float*)d_in[2];
    const float* bq  = (const float*)d_in[3];
    const float* Wk  = (const float*)d_in[4];
    const float* bk  = (const float*)d_in[5];
    const float* Wv  = (const float*)d_in[6];
    const float* bv  = (const float*)d_in[7];
    float* out = (float*)d_out;

    char* ws = (char*)d_ws;
    unsigned short* Xb  = (unsigned short*)(ws);                       // 4 MB
    unsigned short* Wcb = (unsigned short*)(ws + (4ull << 20));        // 384 KB
    unsigned short* Qb  = (unsigned short*)(ws + (5ull << 20));        // 4 MB
    unsigned short* Kb  = (unsigned short*)(ws + (9ull << 20));        // 4 MB
    unsigned short* Vt  = (unsigned short*)(ws + (13ull << 20));       // 4 MB
    unsigned long long* mask64 = (unsigned long long*)(ws + (17ull << 20)); // 4 MB

    cvt_x_kernel<<<dim3(2048), dim3(256), 0, stream>>>(x, Xb);
    cvt_w_kernel<<<dim3(192), dim3(256), 0, stream>>>(Wq, Wk, Wv, Wcb);
    bitpack_kernel<<<dim3(2048), dim3(256), 0, stream>>>(adj, mask64);
    qkv_proj_kernel<<<dim3(128, 12), dim3(256), 0, stream>>>(Xb, Wcb, bq, bk, bv, Qb, Kb, Vt);
    attn_kernel<<<dim3(2048), dim3(256), 0, stream>>>(Qb, Kb, Vt, (const unsigned int*)mask64, out);
}

// Round 5
// 212.475 us; speedup vs baseline: 2.0843x; 2.0843x over previous
//
#include <hip/hip_runtime.h>

typedef __attribute__((ext_vector_type(8))) short short8;
typedef __attribute__((ext_vector_type(4))) float f32x4;
typedef __attribute__((ext_vector_type(4))) unsigned short u16x4;

constexpr int cB = 2, cN = 4096, cE = 256, cH = 8, cHS = 32;

__device__ __forceinline__ unsigned short f2bf(float f) {
    unsigned int u = __builtin_bit_cast(unsigned int, f);
    u = (u + 0x7FFFu + ((u >> 16) & 1u)) >> 16;
    return (unsigned short)u;
}

__device__ __forceinline__ unsigned int cvt_pk_bf16(float lo, float hi) {
    unsigned int r;
    asm("v_cvt_pk_bf16_f32 %0, %1, %2" : "=v"(r) : "v"(lo), "v"(hi));
    return r;
}

// ---- f32 -> bf16 convert: node features (2M elems, 4/thread) ----
__global__ __launch_bounds__(256) void cvt_x_kernel(const float* __restrict__ x,
                                                    unsigned short* __restrict__ xb) {
    int t = blockIdx.x * 256 + threadIdx.x;   // 524288 threads exactly
    f32x4 v = *((const f32x4*)x + t);
    u16x4 o = { f2bf(v[0]), f2bf(v[1]), f2bf(v[2]), f2bf(v[3]) };
    *((u16x4*)xb + t) = o;
}

// ---- f32 -> bf16 convert: Wq|Wk|Wv -> Wcb[768][256] ----
__global__ __launch_bounds__(256) void cvt_w_kernel(const float* __restrict__ Wq,
                                                    const float* __restrict__ Wk,
                                                    const float* __restrict__ Wv,
                                                    unsigned short* __restrict__ wcb) {
    int t = blockIdx.x * 256 + threadIdx.x;   // 49152 threads exactly
    int f = t * 4;
    int o = f >> 8, i = f & 255;
    const float* src = (o < 256) ? Wq : (o < 512 ? Wk : Wv);
    f32x4 v = *(const f32x4*)(src + (size_t)(o & 255) * 256 + i);
    u16x4 ov = { f2bf(v[0]), f2bf(v[1]), f2bf(v[2]), f2bf(v[3]) };
    *((u16x4*)wcb + t) = ov;
}

// ---- adjacency (4-byte elems, nonzero == edge) -> bitmask, 64 bits/wave ----
__global__ __launch_bounds__(256) void bitpack_kernel(const int* __restrict__ adj,
                                                      unsigned long long* __restrict__ mask) {
    int lane = threadIdx.x & 63;
    int wave = blockIdx.x * 4 + (threadIdx.x >> 6);
    const int nwaves = 2048 * 4;
    const int nwords = cB * cN * cN / 64;     // 524288
    for (int w = wave; w < nwords; w += nwaves) {
        int v = adj[(size_t)w * 64 + lane];
        unsigned long long bal = __ballot(v != 0);
        if (lane == 0) mask[w] = bal;
    }
}

// ---- QKV projection: C[8192][768] = Xb @ Wcb^T + bias, MFMA 16x16x32 bf16 ----
// Q stored [b][h][n][32] bf16, PRE-SCALED by log2(e)/sqrt(HS) so attention can
// use exp2 on the raw QK^T output. K stored [b][h][n][32].
// V stored transposed AND k'-permuted within each 32-block of n:
//   Vt[h][hs][ (n&~31) + 2*(n&15) + ((n>>4)&1) ] = V[n][hs]
// so attn's packed (p_c, p_{16+c}) LDS pairs line up with contiguous V loads.
__global__ __launch_bounds__(256) void qkv_proj_kernel(const unsigned short* __restrict__ xb,
                                                       const unsigned short* __restrict__ wcb,
                                                       const float* __restrict__ bq,
                                                       const float* __restrict__ bk,
                                                       const float* __restrict__ bv,
                                                       unsigned short* __restrict__ Qb,
                                                       unsigned short* __restrict__ Kb,
                                                       unsigned short* __restrict__ Vt) {
    const int wv = threadIdx.x >> 6, lane = threadIdx.x & 63;
    const int col = lane & 15, grp = lane >> 4;
    const int rowbase = blockIdx.x * 64 + wv * 16;   // 16 rows per wave
    const int colbase = blockIdx.y * 64;             // 64 cols per block
    const float CE = 1.4426950408889634f * 0.17677669529663687f;  // log2(e)/sqrt(32)
    f32x4 acc[4] = {};
    for (int kk = 0; kk < 8; ++kk) {
        short8 a = *(const short8*)(xb + (size_t)(rowbase + col) * 256 + kk * 32 + grp * 8);
        #pragma unroll
        for (int c = 0; c < 4; ++c) {
            short8 bf = *(const short8*)(wcb + (size_t)(colbase + c * 16 + col) * 256 + kk * 32 + grp * 8);
            acc[c] = __builtin_amdgcn_mfma_f32_16x16x32_bf16(a, bf, acc[c], 0, 0, 0);
        }
    }
    #pragma unroll
    for (int c = 0; c < 4; ++c) {
        const int o = colbase + c * 16 + col;        // lane's output column
        const int sel = o >> 8, oo = o & 255;
        const float bias = (sel == 0 ? bq : sel == 1 ? bk : bv)[oo];
        const int h = oo >> 5, hs = oo & 31;
        const int R0 = rowbase + grp * 4;            // 4 consecutive rows per lane
        const int b = R0 >> 12, n0 = R0 & 4095;
        if (sel == 0) {
            #pragma unroll
            for (int r = 0; r < 4; ++r)
                Qb[(size_t)((b * cH + h) * cN + n0 + r) * cHS + hs] = f2bf((acc[c][r] + bias) * CE);
        } else if (sel == 1) {
            #pragma unroll
            for (int r = 0; r < 4; ++r)
                Kb[(size_t)((b * cH + h) * cN + n0 + r) * cHS + hs] = f2bf(acc[c][r] + bias);
        } else {
            unsigned short* vrow = Vt + (size_t)((b * cH + h) * cHS + hs) * cN;
            #pragma unroll
            for (int r = 0; r < 4; ++r) {
                const int n = n0 + r;
                const int pos = (n & ~31) + 2 * (n & 15) + ((n >> 4) & 1);
                vrow[pos] = f2bf(acc[c][r] + bias);
            }
        }
    }
}

// ---- Flash attention, fixed-max softmax (m=0), bit-masking. ----
// Grid = 1024 blocks; each block = 4 waves does TWO q-tile tasks sequentially
// (qt and qt+64 of the same head -> K/V stay L2-hot). Within a task, the 4
// waves split the key range (wave wv: kt in [wv*32, wv*32+32)). K/V/mask for
// kt+1 are software-prefetched into registers during kt's compute. Partials
// are additive under fixed-max softmax; combined through LDS per task.
// 4 blocks/CU co-resident, all uniform duration -> no tail round.
__global__ __launch_bounds__(256, 4) void attn_kernel(const unsigned short* __restrict__ Qb,
                                                      const unsigned short* __restrict__ Kb,
                                                      const unsigned short* __restrict__ Vt,
                                                      const unsigned int* __restrict__ mask32,
                                                      float* __restrict__ out) {
    // comb doubles as: per-wave P staging during the loop (2560 B at wv*2560),
    // then [wv][lane][24] f32 partial buffer for the combine.
    __shared__ float comb[4][64][24];
    const int wv = threadIdx.x >> 6, lane = threadIdx.x & 63;
    const int col = lane & 15, grp = lane >> 4;
    int bid = blockIdx.x;
    bid = (bid & 7) * 128 + (bid >> 3);              // XCD chunk swizzle (1024 = 8*128)
    const int qt0 = bid & 63, h = (bid >> 6) & 7, b = bid >> 9;
    const unsigned short* Qh = Qb + (size_t)(b * cH + h) * cN * cHS;
    const unsigned short* Kh = Kb + (size_t)(b * cH + h) * cN * cHS;
    const unsigned short* Vh = Vt + (size_t)(b * cH + h) * cHS * cN;
    // per-wave P staging area: [qs][16 rows][20 u32], row stride 80B
    unsigned int* pw = (unsigned int*)&comb[0][0][0] + wv * 640;
    const f32x4 z4 = {0.f, 0.f, 0.f, 0.f};
    const short8 ones = { 0x3F80, 0x3F80, 0x3F80, 0x3F80, 0x3F80, 0x3F80, 0x3F80, 0x3F80 };
    const int kt0 = wv * 32;

    #pragma unroll 1
    for (int tk = 0; tk < 2; ++tk) {
        const int qbase = (qt0 + tk * 64) * 32;
        const unsigned int* mrow = mask32 + (size_t)(b * cN + qbase) * 128;

        const short8 aq0 = *(const short8*)(Qh + (size_t)(qbase + col) * cHS + grp * 8);
        const short8 aq1 = *(const short8*)(Qh + (size_t)(qbase + 16 + col) * cHS + grp * 8);

        f32x4 acc[2][2] = {};
        f32x4 lacc[2] = {};                          // row-sums via ones-MFMA

        // prefetch kt = kt0
        short8 ck0 = *(const short8*)(Kh + (size_t)(kt0 * 32 + col) * cHS + grp * 8);
        short8 ck1 = *(const short8*)(Kh + (size_t)(kt0 * 32 + 16 + col) * cHS + grp * 8);
        short8 cv0 = *(const short8*)(Vh + (size_t)col * cN + kt0 * 32 + grp * 8);
        short8 cv1 = *(const short8*)(Vh + (size_t)(16 + col) * cN + kt0 * 32 + grp * 8);
        unsigned int cm[8];
        #pragma unroll
        for (int i = 0; i < 8; ++i)
            cm[i] = mrow[(size_t)((i >> 2) * 16 + grp * 4 + (i & 3)) * 128 + kt0];

        #pragma unroll 2
        for (int kt = kt0; kt < kt0 + 32; ++kt) {
            const short8 k0 = ck0, k1 = ck1, v0 = cv0, v1 = cv1;
            unsigned int m8[8];
            #pragma unroll
            for (int i = 0; i < 8; ++i) m8[i] = cm[i];
            if (kt < kt0 + 31) {
                const int kb = (kt + 1) * 32;
                ck0 = *(const short8*)(Kh + (size_t)(kb + col) * cHS + grp * 8);
                ck1 = *(const short8*)(Kh + (size_t)(kb + 16 + col) * cHS + grp * 8);
                cv0 = *(const short8*)(Vh + (size_t)col * cN + kb + grp * 8);
                cv1 = *(const short8*)(Vh + (size_t)(16 + col) * cN + kb + grp * 8);
                #pragma unroll
                for (int i = 0; i < 8; ++i)
                    cm[i] = mrow[(size_t)((i >> 2) * 16 + grp * 4 + (i & 3)) * 128 + kt + 1];
            }

            f32x4 s[2][2];
            s[0][0] = __builtin_amdgcn_mfma_f32_16x16x32_bf16(aq0, k0, z4, 0, 0, 0);
            s[0][1] = __builtin_amdgcn_mfma_f32_16x16x32_bf16(aq0, k1, z4, 0, 0, 0);
            s[1][0] = __builtin_amdgcn_mfma_f32_16x16x32_bf16(aq1, k0, z4, 0, 0, 0);
            s[1][1] = __builtin_amdgcn_mfma_f32_16x16x32_bf16(aq1, k1, z4, 0, 0, 0);

            #pragma unroll
            for (int qs = 0; qs < 2; ++qs) {
                #pragma unroll
                for (int r = 0; r < 4; ++r) {
                    const unsigned int w32 = m8[qs * 4 + r];
                    const float e0 = __builtin_exp2f(s[qs][0][r]);
                    const float e1 = __builtin_exp2f(s[qs][1][r]);
                    const unsigned int msk = ((w32 >> col) & 0x00010001u) * 0xFFFFu;
                    pw[qs * 320 + (grp * 4 + r) * 20 + col] = cvt_pk_bf16(e0, e1) & msk;
                }
            }
            #pragma unroll
            for (int qs = 0; qs < 2; ++qs) {
                const short8 pa = *(const short8*)(pw + qs * 320 + col * 20 + grp * 4);
                acc[qs][0] = __builtin_amdgcn_mfma_f32_16x16x32_bf16(pa, v0, acc[qs][0], 0, 0, 0);
                acc[qs][1] = __builtin_amdgcn_mfma_f32_16x16x32_bf16(pa, v1, acc[qs][1], 0, 0, 0);
                lacc[qs]   = __builtin_amdgcn_mfma_f32_16x16x32_bf16(pa, ones, lacc[qs], 0, 0, 0);
            }
        }

        __syncthreads();                             // all waves done with P areas
        float* me = &comb[wv][lane][0];
        *(f32x4*)(me +  0) = acc[0][0];
        *(f32x4*)(me +  4) = acc[0][1];
        *(f32x4*)(me +  8) = acc[1][0];
        *(f32x4*)(me + 12) = acc[1][1];
        *(f32x4*)(me + 16) = lacc[0];
        *(f32x4*)(me + 20) = lacc[1];
        __syncthreads();

        // combine: wave sg handles (qs = sg>>1, half = sg&1)
        const int sg = wv, qs2 = sg >> 1, half = sg & 1;
        f32x4 a = {0.f, 0.f, 0.f, 0.f};
        f32x4 l = {0.f, 0.f, 0.f, 0.f};
        #pragma unroll
        for (int w = 0; w < 4; ++w) {
            a += *(const f32x4*)&comb[w][lane][sg * 4];
            l += *(const f32x4*)&comb[w][lane][16 + qs2 * 4];
        }
        const int row0 = qbase + qs2 * 16 + grp * 4;
        #pragma unroll
        for (int j = 0; j < 4; ++j) {
            out[(size_t)(b * cN + row0 + j) * cE + h * 32 + half * 16 + col] = a[j] / l[j];
        }
        __syncthreads();                             // protect P area for next task
    }
}

extern "C" void kernel_launch(void* const* d_in, const int* in_sizes, int n_in,
                              void* d_out, int out_size, void* d_ws, size_t ws_size,
                              hipStream_t stream) {
    const float* x   = (const float*)d_in[0];
    const int*   adj = (const int*)d_in[1];
    const float* Wq  = (const float*)d_in[2];
    const float* bq  = (const float*)d_in[3];
    const float* Wk  = (const float*)d_in[4];
    const float* bk  = (const float*)d_in[5];
    const float* Wv  = (const float*)d_in[6];
    const float* bv  = (const float*)d_in[7];
    float* out = (float*)d_out;

    char* ws = (char*)d_ws;
    unsigned short* Xb  = (unsigned short*)(ws);                       // 4 MB
    unsigned short* Wcb = (unsigned short*)(ws + (4ull << 20));        // 384 KB
    unsigned short* Qb  = (unsigned short*)(ws + (5ull << 20));        // 4 MB
    unsigned short* Kb  = (unsigned short*)(ws + (9ull << 20));        // 4 MB
    unsigned short* Vt  = (unsigned short*)(ws + (13ull << 20));       // 4 MB
    unsigned long long* mask64 = (unsigned long long*)(ws + (17ull << 20)); // 4 MB

    cvt_x_kernel<<<dim3(2048), dim3(256), 0, stream>>>(x, Xb);
    cvt_w_kernel<<<dim3(192), dim3(256), 0, stream>>>(Wq, Wk, Wv, Wcb);
    bitpack_kernel<<<dim3(2048), dim3(256), 0, stream>>>(adj, mask64);
    qkv_proj_kernel<<<dim3(128, 12), dim3(256), 0, stream>>>(Xb, Wcb, bq, bk, bv, Qb, Kb, Vt);
    attn_kernel<<<dim3(1024), dim3(256), 0, stream>>>(Qb, Kb, Vt, (const unsigned int*)mask64, out);
}

// Round 6
// 199.199 us; speedup vs baseline: 2.2233x; 1.0667x over previous
//
#include <hip/hip_runtime.h>

typedef __attribute__((ext_vector_type(8))) short short8;
typedef __attribute__((ext_vector_type(4))) float f32x4;
typedef __attribute__((ext_vector_type(4))) unsigned short u16x4;

constexpr int cB = 2, cN = 4096, cE = 256, cH = 8, cHS = 32;

__device__ __forceinline__ unsigned short f2bf(float f) {
    unsigned int u = __builtin_bit_cast(unsigned int, f);
    u = (u + 0x7FFFu + ((u >> 16) & 1u)) >> 16;
    return (unsigned short)u;
}

__device__ __forceinline__ unsigned int cvt_pk_bf16(float lo, float hi) {
    unsigned int r;
    asm("v_cvt_pk_bf16_f32 %0, %1, %2" : "=v"(r) : "v"(lo), "v"(hi));
    return r;
}

// ---- f32 -> bf16 convert: node features (2M elems, 4/thread) ----
__global__ __launch_bounds__(256) void cvt_x_kernel(const float* __restrict__ x,
                                                    unsigned short* __restrict__ xb) {
    int t = blockIdx.x * 256 + threadIdx.x;   // 524288 threads exactly
    f32x4 v = *((const f32x4*)x + t);
    u16x4 o = { f2bf(v[0]), f2bf(v[1]), f2bf(v[2]), f2bf(v[3]) };
    *((u16x4*)xb + t) = o;
}

// ---- f32 -> bf16 convert: Wq|Wk|Wv -> Wcb[768][256] ----
__global__ __launch_bounds__(256) void cvt_w_kernel(const float* __restrict__ Wq,
                                                    const float* __restrict__ Wk,
                                                    const float* __restrict__ Wv,
                                                    unsigned short* __restrict__ wcb) {
    int t = blockIdx.x * 256 + threadIdx.x;   // 49152 threads exactly
    int f = t * 4;
    int o = f >> 8, i = f & 255;
    const float* src = (o < 256) ? Wq : (o < 512 ? Wk : Wv);
    f32x4 v = *(const f32x4*)(src + (size_t)(o & 255) * 256 + i);
    u16x4 ov = { f2bf(v[0]), f2bf(v[1]), f2bf(v[2]), f2bf(v[3]) };
    *((u16x4*)wcb + t) = ov;
}

// ---- adjacency (4-byte elems, nonzero == edge) -> bitmask, 64 bits/wave ----
__global__ __launch_bounds__(256) void bitpack_kernel(const int* __restrict__ adj,
                                                      unsigned long long* __restrict__ mask) {
    int lane = threadIdx.x & 63;
    int wave = blockIdx.x * 4 + (threadIdx.x >> 6);
    const int nwaves = 2048 * 4;
    const int nwords = cB * cN * cN / 64;     // 524288
    for (int w = wave; w < nwords; w += nwaves) {
        int v = adj[(size_t)w * 64 + lane];
        unsigned long long bal = __ballot(v != 0);
        if (lane == 0) mask[w] = bal;
    }
}

// ---- QKV projection: C[8192][768] = Xb @ Wcb^T + bias, MFMA 16x16x32 bf16 ----
// Q stored [b][h][n][32] bf16, PRE-SCALED by log2(e)/sqrt(HS) so attention can
// use exp2 on the raw QK^T output. K stored [b][h][n][32].
// V stored transposed AND k'-permuted within each 32-block of n:
//   Vt[h][hs][ (n&~31) + 2*(n&15) + ((n>>4)&1) ] = V[n][hs]
// so attn's packed (p_c, p_{16+c}) LDS pairs line up with contiguous V loads.
__global__ __launch_bounds__(256) void qkv_proj_kernel(const unsigned short* __restrict__ xb,
                                                       const unsigned short* __restrict__ wcb,
                                                       const float* __restrict__ bq,
                                                       const float* __restrict__ bk,
                                                       const float* __restrict__ bv,
                                                       unsigned short* __restrict__ Qb,
                                                       unsigned short* __restrict__ Kb,
                                                       unsigned short* __restrict__ Vt) {
    const int wv = threadIdx.x >> 6, lane = threadIdx.x & 63;
    const int col = lane & 15, grp = lane >> 4;
    const int rowbase = blockIdx.x * 64 + wv * 16;   // 16 rows per wave
    const int colbase = blockIdx.y * 64;             // 64 cols per block
    const float CE = 1.4426950408889634f * 0.17677669529663687f;  // log2(e)/sqrt(32)
    f32x4 acc[4] = {};
    for (int kk = 0; kk < 8; ++kk) {
        short8 a = *(const short8*)(xb + (size_t)(rowbase + col) * 256 + kk * 32 + grp * 8);
        #pragma unroll
        for (int c = 0; c < 4; ++c) {
            short8 bf = *(const short8*)(wcb + (size_t)(colbase + c * 16 + col) * 256 + kk * 32 + grp * 8);
            acc[c] = __builtin_amdgcn_mfma_f32_16x16x32_bf16(a, bf, acc[c], 0, 0, 0);
        }
    }
    #pragma unroll
    for (int c = 0; c < 4; ++c) {
        const int o = colbase + c * 16 + col;        // lane's output column
        const int sel = o >> 8, oo = o & 255;
        const float bias = (sel == 0 ? bq : sel == 1 ? bk : bv)[oo];
        const int h = oo >> 5, hs = oo & 31;
        const int R0 = rowbase + grp * 4;            // 4 consecutive rows per lane
        const int b = R0 >> 12, n0 = R0 & 4095;
        if (sel == 0) {
            #pragma unroll
            for (int r = 0; r < 4; ++r)
                Qb[(size_t)((b * cH + h) * cN + n0 + r) * cHS + hs] = f2bf((acc[c][r] + bias) * CE);
        } else if (sel == 1) {
            #pragma unroll
            for (int r = 0; r < 4; ++r)
                Kb[(size_t)((b * cH + h) * cN + n0 + r) * cHS + hs] = f2bf(acc[c][r] + bias);
        } else {
            unsigned short* vrow = Vt + (size_t)((b * cH + h) * cHS + hs) * cN;
            #pragma unroll
            for (int r = 0; r < 4; ++r) {
                const int n = n0 + r;
                const int pos = (n & ~31) + 2 * (n & 15) + ((n >> 4) & 1);
                vrow[pos] = f2bf(acc[c][r] + bias);
            }
        }
    }
}

// ---- Flash attention, fixed-max softmax (m=0), bit-masking. ----
// Grid = 1024 blocks; each block = 4 waves does TWO q-tile tasks sequentially.
// Within a task, waves split the key range (wave wv: kt in [wv*32,wv*32+32)).
// Inner loop is software-pipelined ONE step: iteration kt computes QK^T(kt)
// and exp/pack(kt) on the VALU while the PV/lacc MFMAs consume P(kt-1) from
// LDS -- the exp chain overlaps the MFMA pipe instead of serializing with it.
// Only K is prefetched one kt ahead; V is naturally one-ahead (loaded at kt,
// consumed at kt+1). Register budget kept ~112 total (4 waves/SIMD legal).
__global__ __launch_bounds__(256, 4) void attn_kernel(const unsigned short* __restrict__ Qb,
                                                      const unsigned short* __restrict__ Kb,
                                                      const unsigned short* __restrict__ Vt,
                                                      const unsigned int* __restrict__ mask32,
                                                      float* __restrict__ out) {
    // comb doubles as: per-wave P staging during the loop (2560 B at wv*2560),
    // then [wv][lane][24] f32 partial buffer for the combine.
    __shared__ float comb[4][64][24];
    const int wv = threadIdx.x >> 6, lane = threadIdx.x & 63;
    const int col = lane & 15, grp = lane >> 4;
    int bid = blockIdx.x;
    bid = (bid & 7) * 128 + (bid >> 3);              // XCD chunk swizzle (1024 = 8*128)
    const int qt0 = bid & 63, h = (bid >> 6) & 7, b = bid >> 9;
    const unsigned short* Qh = Qb + (size_t)(b * cH + h) * cN * cHS;
    const unsigned short* Kh = Kb + (size_t)(b * cH + h) * cN * cHS;
    const unsigned short* Vh = Vt + (size_t)(b * cH + h) * cHS * cN;
    // per-wave P staging area: [qs][16 rows][20 u32], row stride 80B
    unsigned int* pw = (unsigned int*)&comb[0][0][0] + wv * 640;
    const f32x4 z4 = {0.f, 0.f, 0.f, 0.f};
    const short8 ones = { 0x3F80, 0x3F80, 0x3F80, 0x3F80, 0x3F80, 0x3F80, 0x3F80, 0x3F80 };
    const int kt0 = wv * 32;

    #pragma unroll 1
    for (int tk = 0; tk < 2; ++tk) {
        const int qbase = (qt0 + tk * 64) * 32;
        const unsigned int* mrow = mask32 + (size_t)(b * cN + qbase) * 128;

        const short8 aq0 = *(const short8*)(Qh + (size_t)(qbase + col) * cHS + grp * 8);
        const short8 aq1 = *(const short8*)(Qh + (size_t)(qbase + 16 + col) * cHS + grp * 8);

        f32x4 acc[2][2] = {};
        f32x4 lacc[2] = {};                          // row-sums via ones-MFMA

        // ---- peel kt = kt0: QK + exp + write P (no PV yet) ----
        short8 kc0 = *(const short8*)(Kh + (size_t)(kt0 * 32 + col) * cHS + grp * 8);
        short8 kc1 = *(const short8*)(Kh + (size_t)(kt0 * 32 + 16 + col) * cHS + grp * 8);
        short8 vp0 = *(const short8*)(Vh + (size_t)col * cN + kt0 * 32 + grp * 8);
        short8 vp1 = *(const short8*)(Vh + (size_t)(16 + col) * cN + kt0 * 32 + grp * 8);
        {
            f32x4 s[2][2];
            s[0][0] = __builtin_amdgcn_mfma_f32_16x16x32_bf16(aq0, kc0, z4, 0, 0, 0);
            s[0][1] = __builtin_amdgcn_mfma_f32_16x16x32_bf16(aq0, kc1, z4, 0, 0, 0);
            s[1][0] = __builtin_amdgcn_mfma_f32_16x16x32_bf16(aq1, kc0, z4, 0, 0, 0);
            s[1][1] = __builtin_amdgcn_mfma_f32_16x16x32_bf16(aq1, kc1, z4, 0, 0, 0);
            #pragma unroll
            for (int qs = 0; qs < 2; ++qs)
                #pragma unroll
                for (int r = 0; r < 4; ++r) {
                    const unsigned int w32 = mrow[(size_t)(qs * 16 + grp * 4 + r) * 128 + kt0];
                    const float e0 = __builtin_exp2f(s[qs][0][r]);
                    const float e1 = __builtin_exp2f(s[qs][1][r]);
                    const unsigned int msk = ((w32 >> col) & 0x00010001u) * 0xFFFFu;
                    pw[qs * 320 + (grp * 4 + r) * 20 + col] = cvt_pk_bf16(e0, e1) & msk;
                }
        }
        // prefetch K(kt0+1)
        short8 kn0 = *(const short8*)(Kh + (size_t)((kt0 + 1) * 32 + col) * cHS + grp * 8);
        short8 kn1 = *(const short8*)(Kh + (size_t)((kt0 + 1) * 32 + 16 + col) * cHS + grp * 8);

        // ---- pipelined main loop: QK/exp for kt, PV for kt-1 ----
        #pragma unroll 1
        for (int kt = kt0 + 1; kt < kt0 + 32; ++kt) {
            const short8 k0 = kn0, k1 = kn1;
            // issue next-K / cur-V / cur-mask loads early (unconditional;
            // kt+1 == 128 for wv=3 reads past this head's K -- mapped ws
            // memory, value never used)
            const int kb1 = (kt + 1) * 32;
            kn0 = *(const short8*)(Kh + (size_t)(kb1 + col) * cHS + grp * 8);
            kn1 = *(const short8*)(Kh + (size_t)(kb1 + 16 + col) * cHS + grp * 8);
            const short8 vc0 = *(const short8*)(Vh + (size_t)col * cN + kt * 32 + grp * 8);
            const short8 vc1 = *(const short8*)(Vh + (size_t)(16 + col) * cN + kt * 32 + grp * 8);
            unsigned int m8[8];
            #pragma unroll
            for (int i = 0; i < 8; ++i)
                m8[i] = mrow[(size_t)((i >> 2) * 16 + grp * 4 + (i & 3)) * 128 + kt];

            f32x4 s[2][2];
            s[0][0] = __builtin_amdgcn_mfma_f32_16x16x32_bf16(aq0, k0, z4, 0, 0, 0);
            s[0][1] = __builtin_amdgcn_mfma_f32_16x16x32_bf16(aq0, k1, z4, 0, 0, 0);
            s[1][0] = __builtin_amdgcn_mfma_f32_16x16x32_bf16(aq1, k0, z4, 0, 0, 0);
            s[1][1] = __builtin_amdgcn_mfma_f32_16x16x32_bf16(aq1, k1, z4, 0, 0, 0);

            // PV + lacc for kt-1 (P already in LDS, V in vp regs) --
            // independent of s/exp chain, fills the MFMA pipe under the exps
            #pragma unroll
            for (int qs = 0; qs < 2; ++qs) {
                const short8 pa = *(const short8*)(pw + qs * 320 + col * 20 + grp * 4);
                acc[qs][0] = __builtin_amdgcn_mfma_f32_16x16x32_bf16(pa, vp0, acc[qs][0], 0, 0, 0);
                acc[qs][1] = __builtin_amdgcn_mfma_f32_16x16x32_bf16(pa, vp1, acc[qs][1], 0, 0, 0);
                lacc[qs]   = __builtin_amdgcn_mfma_f32_16x16x32_bf16(pa, ones, lacc[qs], 0, 0, 0);
            }

            #pragma unroll
            for (int qs = 0; qs < 2; ++qs)
                #pragma unroll
                for (int r = 0; r < 4; ++r) {
                    const unsigned int w32 = m8[qs * 4 + r];
                    const float e0 = __builtin_exp2f(s[qs][0][r]);
                    const float e1 = __builtin_exp2f(s[qs][1][r]);
                    const unsigned int msk = ((w32 >> col) & 0x00010001u) * 0xFFFFu;
                    pw[qs * 320 + (grp * 4 + r) * 20 + col] = cvt_pk_bf16(e0, e1) & msk;
                }
            vp0 = vc0; vp1 = vc1;
        }
        // ---- epilogue: PV for kt = kt0+31 ----
        #pragma unroll
        for (int qs = 0; qs < 2; ++qs) {
            const short8 pa = *(const short8*)(pw + qs * 320 + col * 20 + grp * 4);
            acc[qs][0] = __builtin_amdgcn_mfma_f32_16x16x32_bf16(pa, vp0, acc[qs][0], 0, 0, 0);
            acc[qs][1] = __builtin_amdgcn_mfma_f32_16x16x32_bf16(pa, vp1, acc[qs][1], 0, 0, 0);
            lacc[qs]   = __builtin_amdgcn_mfma_f32_16x16x32_bf16(pa, ones, lacc[qs], 0, 0, 0);
        }

        __syncthreads();                             // all waves done with P areas
        float* me = &comb[wv][lane][0];
        *(f32x4*)(me +  0) = acc[0][0];
        *(f32x4*)(me +  4) = acc[0][1];
        *(f32x4*)(me +  8) = acc[1][0];
        *(f32x4*)(me + 12) = acc[1][1];
        *(f32x4*)(me + 16) = lacc[0];
        *(f32x4*)(me + 20) = lacc[1];
        __syncthreads();

        // combine: wave sg handles (qs = sg>>1, half = sg&1)
        const int sg = wv, qs2 = sg >> 1, half = sg & 1;
        f32x4 a = {0.f, 0.f, 0.f, 0.f};
        f32x4 l = {0.f, 0.f, 0.f, 0.f};
        #pragma unroll
        for (int w = 0; w < 4; ++w) {
            a += *(const f32x4*)&comb[w][lane][sg * 4];
            l += *(const f32x4*)&comb[w][lane][16 + qs2 * 4];
        }
        const int row0 = qbase + qs2 * 16 + grp * 4;
        #pragma unroll
        for (int j = 0; j < 4; ++j) {
            out[(size_t)(b * cN + row0 + j) * cE + h * 32 + half * 16 + col] = a[j] / l[j];
        }
        __syncthreads();                             // protect P area for next task
    }
}

extern "C" void kernel_launch(void* const* d_in, const int* in_sizes, int n_in,
                              void* d_out, int out_size, void* d_ws, size_t ws_size,
                              hipStream_t stream) {
    const float* x   = (const float*)d_in[0];
    const int*   adj = (const int*)d_in[1];
    const float* Wq  = (const float*)d_in[2];
    const float* bq  = (const float*)d_in[3];
    const float* Wk  = (const float*)d_in[4];
    const float* bk  = (const float*)d_in[5];
    const float* Wv  = (const float*)d_in[6];
    const float* bv  = (const float*)d_in[7];
    float* out = (float*)d_out;

    char* ws = (char*)d_ws;
    unsigned short* Xb  = (unsigned short*)(ws);                       // 4 MB
    unsigned short* Wcb = (unsigned short*)(ws + (4ull << 20));        // 384 KB
    unsigned short* Qb  = (unsigned short*)(ws + (5ull << 20));        // 4 MB
    unsigned short* Kb  = (unsigned short*)(ws + (9ull << 20));        // 4 MB
    unsigned short* Vt  = (unsigned short*)(ws + (13ull << 20));       // 4 MB
    unsigned long long* mask64 = (unsigned long long*)(ws + (17ull << 20)); // 4 MB

    cvt_x_kernel<<<dim3(2048), dim3(256), 0, stream>>>(x, Xb);
    cvt_w_kernel<<<dim3(192), dim3(256), 0, stream>>>(Wq, Wk, Wv, Wcb);
    bitpack_kernel<<<dim3(2048), dim3(256), 0, stream>>>(adj, mask64);
    qkv_proj_kernel<<<dim3(128, 12), dim3(256), 0, stream>>>(Xb, Wcb, bq, bk, bv, Qb, Kb, Vt);
    attn_kernel<<<dim3(1024), dim3(256), 0, stream>>>(Qb, Kb, Vt, (const unsigned int*)mask64, out);
}